// Round 7
// baseline (58.763 us; speedup 1.0000x reference)
//
#include <hip/hip_runtime.h>
#include <hip/hip_bf16.h>

typedef __bf16 bf16_t;
typedef __bf16 bf16x4 __attribute__((ext_vector_type(4)));
typedef __bf16 bf16x8 __attribute__((ext_vector_type(8)));
typedef float  f32x4  __attribute__((ext_vector_type(4)));

static constexpr int Mtot = 4096;   // B*S
static constexpr int Ntot = 1024;   // H*A
static constexpr int Ktot = 1024;   // F

// out[b,s,h,a] = sum_f value_input[b,s,f] * v_w[h,f,a]
// (reference softmax over q integrates to exactly 1 in the final q-contraction)

// ============================================================================
// Prepass: Ab = bf16(A) [4096][1024]; Wt = bf16 transpose of W: [n=h*64+a][k]
// (proven correct in R3/R4)
// ============================================================================
__global__ __launch_bounds__(256)
void prepass_kernel(const float* __restrict__ A, const float* __restrict__ W,
                    bf16_t* __restrict__ Ab, bf16_t* __restrict__ Wt)
{
    __shared__ float wtile[64][65];
    const int bid = blockIdx.x, t = threadIdx.x;

    if (bid < 1024) {
        const size_t base = (size_t)bid * 4096 + t * 4;
#pragma unroll
        for (int r = 0; r < 4; ++r) {
            const size_t i = base + (size_t)r * 1024;
            const f32x4 v = *(const f32x4*)(A + i);
            bf16x4 p = {(bf16_t)v[0], (bf16_t)v[1], (bf16_t)v[2], (bf16_t)v[3]};
            *(bf16x4*)(Ab + i) = p;
        }
    } else {
        const int wb = bid - 1024;        // 0..255
        const int head = wb >> 4;
        const int k0 = (wb & 15) * 64;
        const float* wsrc = W + (size_t)head * (Ktot * 64) + (size_t)k0 * 64;
#pragma unroll
        for (int i = 0; i < 4; ++i) {
            const int idx = i * 256 + t;
            const int kr = idx >> 4, a4 = (idx & 15) * 4;
            const f32x4 v = *(const f32x4*)(wsrc + (size_t)kr * 64 + a4);
            wtile[kr][a4 + 0] = v[0]; wtile[kr][a4 + 1] = v[1];
            wtile[kr][a4 + 2] = v[2]; wtile[kr][a4 + 3] = v[3];
        }
        __syncthreads();
#pragma unroll
        for (int i = 0; i < 4; ++i) {
            const int idx = i * 256 + t;
            const int ar = idx >> 4, kc = (idx & 15) * 4;
            bf16x4 p = {(bf16_t)wtile[kc + 0][ar], (bf16_t)wtile[kc + 1][ar],
                        (bf16_t)wtile[kc + 2][ar], (bf16_t)wtile[kc + 3][ar]};
            *(bf16x4*)(Wt + (size_t)(head * 64 + ar) * Ktot + k0 + kc) = p;
        }
    }
}

// ============================================================================
// Barrier-free direct-global GEMM. No LDS. Wave-tile 64x32 (acc 4x2 frags);
// block = 4 waves side-by-side in N (block tile 64x128, A-frags shared -> L1).
// Fragments are 8 k-contiguous bf16 per lane, loaded straight from Ab/Wt with
// per-row base pointers + compile-time byte offsets (K*2B = 2048 <= imm13).
// Grid 512 = 2 blocks/CU. Fully unrolled K-loop; compiler pipelines freely.
// ============================================================================
__global__ __launch_bounds__(256, 2)
void gemm_direct_kernel(const bf16_t* __restrict__ Ab,
                        const bf16_t* __restrict__ Wt,
                        float* __restrict__ C)
{
    const int t = threadIdx.x, lane = t & 63, wn = t >> 6;

    // XCD swizzle: 512 wgs; XCD x owns 64 consecutive tiles = M-band 512 rows
    // (A-band 1 MB + Wt 2 MB resident in its L2)
    const int g  = (blockIdx.x & 7) * 64 + (blockIdx.x >> 3);
    const int by = g >> 3, bx = g & 7;
    const int bm = by * 64;
    const int bn = bx * 128 + wn * 32;

    const int lrow = lane & 15, lq = lane >> 4;

    // per-row fragment base pointers (fold lq into base; k becomes imm offset)
    const bf16_t* ap[4];
#pragma unroll
    for (int mf = 0; mf < 4; ++mf)
        ap[mf] = Ab + (size_t)(bm + mf * 16 + lrow) * Ktot + lq * 8;
    const bf16_t* bp[2];
#pragma unroll
    for (int nf = 0; nf < 2; ++nf)
        bp[nf] = Wt + (size_t)(bn + nf * 16 + lrow) * Ktot + lq * 8;

    f32x4 acc[4][2];
#pragma unroll
    for (int mf = 0; mf < 4; ++mf)
#pragma unroll
        for (int nf = 0; nf < 2; ++nf) {
            f32x4 z = {0.f, 0.f, 0.f, 0.f};
            acc[mf][nf] = z;
        }

#pragma unroll
    for (int tI = 0; tI < Ktot / 64; ++tI) {      // 16 steps, fully unrolled
#pragma unroll
        for (int kk = 0; kk < 2; ++kk) {
            const int off = tI * 64 + kk * 32;     // elements; *2 = bytes <= 2048
            bf16x8 af[4], bfr[2];
#pragma unroll
            for (int mf = 0; mf < 4; ++mf)
                af[mf] = *(const bf16x8*)(ap[mf] + off);
#pragma unroll
            for (int nf = 0; nf < 2; ++nf)
                bfr[nf] = *(const bf16x8*)(bp[nf] + off);
            __builtin_amdgcn_s_setprio(1);
#pragma unroll
            for (int mf = 0; mf < 4; ++mf)
#pragma unroll
                for (int nf = 0; nf < 2; ++nf)
                    acc[mf][nf] = __builtin_amdgcn_mfma_f32_16x16x32_bf16(
                        af[mf], bfr[nf], acc[mf][nf], 0, 0, 0);
            __builtin_amdgcn_s_setprio(0);
        }
    }

    // epilogue: C/D layout col = lane&15, row = (lane>>4)*4 + i
#pragma unroll
    for (int mf = 0; mf < 4; ++mf) {
        const int row0 = bm + mf * 16 + (lq << 2);
#pragma unroll
        for (int nf = 0; nf < 2; ++nf) {
            const int col = bn + nf * 16 + lrow;
#pragma unroll
            for (int i = 0; i < 4; ++i)
                C[(size_t)(row0 + i) * Ntot + col] = acc[mf][nf][i];
        }
    }
}

// ============================================================================
// Fallback (ws too small): round-2 fused kernel (proven correct, ~33 us)
// ============================================================================
static constexpr int FBM = 128, FBN = 128, FBK = 64, FBKP = 72;

__global__ __launch_bounds__(512, 2)
void vproj_fused_kernel(const float* __restrict__ A, const float* __restrict__ W,
                        float* __restrict__ C)
{
    __shared__ bf16_t As[2][FBM][FBKP];
    __shared__ bf16_t Bs[2][FBN][FBKP];

    const int t = threadIdx.x, lane = t & 63, wave = t >> 6;
    const int wm = wave >> 2, wn = wave & 3;
    const int tile = (blockIdx.x & 7) * 32 + (blockIdx.x >> 3);
    const int bm = (tile >> 3) * FBM, bn = (tile & 7) * FBN;

    const int bhead = t >> 8, brem = t & 255;
    const int bkq = brem >> 4, baq = brem & 15;
    const float* const wbase = W + ((size_t)((bn >> 6) + bhead)) * (Ktot * 64)
                                 + (size_t)(bkq * 4) * 64 + baq * 4;
    f32x4 avreg[4], bvreg[4];

    auto load_tile = [&](int k0) {
#pragma unroll
        for (int r = 0; r < 4; ++r) {
            const int idx = r * 512 + t;
            avreg[r] = *(const f32x4*)(A + (size_t)(bm + (idx >> 4)) * Ktot + k0 + (idx & 15) * 4);
        }
        const float* wp = wbase + (size_t)k0 * 64;
#pragma unroll
        for (int r = 0; r < 4; ++r) bvreg[r] = *(const f32x4*)(wp + r * 64);
    };
    auto store_tile = [&](int buf) {
#pragma unroll
        for (int r = 0; r < 4; ++r) {
            const int idx = r * 512 + t;
            bf16x4 p = {(bf16_t)avreg[r][0], (bf16_t)avreg[r][1],
                        (bf16_t)avreg[r][2], (bf16_t)avreg[r][3]};
            *(bf16x4*)&As[buf][idx >> 4][(idx & 15) * 4] = p;
        }
#pragma unroll
        for (int j = 0; j < 4; ++j) {
            bf16x4 p = {(bf16_t)bvreg[0][j], (bf16_t)bvreg[1][j],
                        (bf16_t)bvreg[2][j], (bf16_t)bvreg[3][j]};
            *(bf16x4*)&Bs[buf][bhead * 64 + baq * 4 + j][bkq * 4] = p;
        }
    };

    f32x4 acc[4][2];
#pragma unroll
    for (int mf = 0; mf < 4; ++mf)
#pragma unroll
        for (int nf = 0; nf < 2; ++nf) { f32x4 z = {0,0,0,0}; acc[mf][nf] = z; }

    const int lrow = lane & 15, lkb = (lane >> 4) << 3;
    load_tile(0); store_tile(0); __syncthreads();

    for (int tI = 0; tI < Ktot / FBK; ++tI) {
        const int cur = tI & 1;
        if (tI + 1 < Ktot / FBK) load_tile((tI + 1) * FBK);
#pragma unroll
        for (int kk = 0; kk < 2; ++kk) {
            bf16x8 af[4], bfr[2];
#pragma unroll
            for (int mf = 0; mf < 4; ++mf)
                af[mf] = *(const bf16x8*)&As[cur][wm * 64 + mf * 16 + lrow][kk * 32 + lkb];
#pragma unroll
            for (int nf = 0; nf < 2; ++nf)
                bfr[nf] = *(const bf16x8*)&Bs[cur][wn * 32 + nf * 16 + lrow][kk * 32 + lkb];
#pragma unroll
            for (int mf = 0; mf < 4; ++mf)
#pragma unroll
                for (int nf = 0; nf < 2; ++nf)
                    acc[mf][nf] = __builtin_amdgcn_mfma_f32_16x16x32_bf16(
                        af[mf], bfr[nf], acc[mf][nf], 0, 0, 0);
        }
        if (tI + 1 < Ktot / FBK) store_tile(cur ^ 1);
        __syncthreads();
    }
#pragma unroll
    for (int mf = 0; mf < 4; ++mf) {
        const int row0 = bm + wm * 64 + mf * 16 + ((lane >> 4) << 2);
#pragma unroll
        for (int nf = 0; nf < 2; ++nf) {
            const int col = bn + wn * 32 + nf * 16 + (lane & 15);
#pragma unroll
            for (int i = 0; i < 4; ++i)
                C[(size_t)(row0 + i) * Ntot + col] = acc[mf][nf][i];
        }
    }
}

extern "C" void kernel_launch(void* const* d_in, const int* in_sizes, int n_in,
                              void* d_out, int out_size, void* d_ws, size_t ws_size,
                              hipStream_t stream) {
    (void)in_sizes; (void)n_in; (void)out_size;
    const float* V  = (const float*)d_in[2];   // [B,S,F] = [M][K]
    const float* Vw = (const float*)d_in[5];   // [H,F,A]
    float* out      = (float*)d_out;           // [B,S,H,A] = [M][N]

    const size_t abBytes = (size_t)Mtot * Ktot * sizeof(bf16_t);   // 8 MiB
    const size_t wtBytes = (size_t)Ntot * Ktot * sizeof(bf16_t);   // 2 MiB

    if (ws_size >= abBytes + wtBytes) {
        bf16_t* Ab = (bf16_t*)d_ws;
        bf16_t* Wt = (bf16_t*)((char*)d_ws + abBytes);
        hipLaunchKernelGGL(prepass_kernel, dim3(1024 + 256), dim3(256), 0, stream,
                           V, Vw, Ab, Wt);
        hipLaunchKernelGGL(gemm_direct_kernel, dim3(512), dim3(256), 0, stream,
                           Ab, Wt, out);
    } else {
        hipLaunchKernelGGL(vproj_fused_kernel, dim3(256), dim3(512), 0, stream,
                           V, Vw, out);
    }
}

// Round 9
// 35.707 us; speedup vs baseline: 1.6457x; 1.6457x over previous
//
#include <hip/hip_runtime.h>
#include <hip/hip_bf16.h>

typedef __bf16 bf16_t;
typedef __bf16 bf16x8 __attribute__((ext_vector_type(8)));
typedef float  f32x4  __attribute__((ext_vector_type(4)));

static constexpr int Mtot = 4096;   // B*S
static constexpr int Ntot = 1024;   // H*A
static constexpr int Ktot = 1024;   // F

// out[b,s,h,a] = sum_f value_input[b,s,f] * v_w[h,f,a]
// (reference softmax over q integrates to exactly 1 in the final q-contraction)
//
// Fragment-major layout: MFMA frag (16 rows x 32 k) stored contiguously as
// 64 lanes x 16B = 1KB. Element: buf[f*512 + lane*8 + e] where
// lane = (row&15) | ((k>>3)&3)<<4, e = k&7.
// A frags: f = (row>>4)*32 + (k>>5)   (8192 frags, 8 MiB)
// W frags: f = (n>>4)*32 + (k>>5)     (2048 frags, 2 MiB), n = h*64+a

// ============================================================================
// Prepass: emit frag-major bf16 Abf / Wbf. One thread = one 16B lane-chunk.
// Writes perfectly coalesced (consecutive tid -> consecutive 16B).
// ============================================================================
__global__ __launch_bounds__(256)
void prepass_frag_kernel(const float* __restrict__ A, const float* __restrict__ W,
                         bf16_t* __restrict__ Abf, bf16_t* __restrict__ Wbf)
{
    const int bid = blockIdx.x, t = threadIdx.x;
    if (bid < 2048) {
        // A part: idx = frag*64 + lane, 8192 frags
        const int idx = bid * 256 + t;
        const int f = idx >> 6, l = idx & 63;
        const int row = (f >> 5) * 16 + (l & 15);
        const int k0  = (f & 31) * 32 + ((l >> 4) << 3);
        const float* src = A + (size_t)row * Ktot + k0;
        const f32x4 v0 = *(const f32x4*)(src);
        const f32x4 v1 = *(const f32x4*)(src + 4);
        bf16x8 p = {(bf16_t)v0[0], (bf16_t)v0[1], (bf16_t)v0[2], (bf16_t)v0[3],
                    (bf16_t)v1[0], (bf16_t)v1[1], (bf16_t)v1[2], (bf16_t)v1[3]};
        *(bf16x8*)(Abf + (size_t)idx * 8) = p;
    } else {
        // W part: idx = frag*64 + lane, 2048 frags
        const int idx = (bid - 2048) * 256 + t;
        const int f = idx >> 6, l = idx & 63;
        const int n  = (f >> 5) * 16 + (l & 15);
        const int k0 = (f & 31) * 32 + ((l >> 4) << 3);
        const int h = n >> 6, a = n & 63;
        const float* src = W + (size_t)h * (Ktot * 64) + (size_t)k0 * 64 + a;
        float tmp[8];
#pragma unroll
        for (int e = 0; e < 8; ++e) tmp[e] = src[(size_t)e * 64];
        bf16x8 p = {(bf16_t)tmp[0], (bf16_t)tmp[1], (bf16_t)tmp[2], (bf16_t)tmp[3],
                    (bf16_t)tmp[4], (bf16_t)tmp[5], (bf16_t)tmp[6], (bf16_t)tmp[7]};
        *(bf16x8*)(Wbf + (size_t)idx * 8) = p;
    }
}

// ============================================================================
// Barrier-free, LDS-free GEMM on frag-major operands.
// Wave-tile 64x32 (4 A-frags x 2 B-frags); block 2x2 waves -> tile 128x64.
// Grid 512 = 2 blocks/CU = 2 waves/SIMD. Every frag load = contiguous 1KB
// wave-load (base + lane*16). Static 3-buffer, distance-2 prefetch.
// ============================================================================
struct FragBuf { bf16x8 a[4]; bf16x8 b[2]; };

__global__ __launch_bounds__(256, 2)
void gemm_frag_kernel(const bf16_t* __restrict__ Abf,
                      const bf16_t* __restrict__ Wbf,
                      float* __restrict__ C)
{
    const int t = threadIdx.x, lane = t & 63, wave = t >> 6;
    const int wm = wave >> 1, wn = wave & 1;

    // XCD swizzle: 512 wgs; XCD x owns 64 tiles = 4 M-panels x all 16 N
    // (A-slice 1 MB + W 2 MB < 4 MB L2)
    const int g  = (blockIdx.x & 7) * 64 + (blockIdx.x >> 3);
    const int by = g >> 4, bx = g & 15;
    const int bm = by * 128, bn = bx * 64;

    const int lrow = lane & 15, lq = lane >> 4;

    const int R0  = (bm >> 4) + wm * 4;   // first A row-frag
    const int Nn0 = (bn >> 4) + wn * 2;   // first B n-frag

    const bf16_t* const aLane = Abf + (size_t)lane * 8;
    const bf16_t* const bLane = Wbf + (size_t)lane * 8;

    f32x4 acc[4][2];
#pragma unroll
    for (int mf = 0; mf < 4; ++mf)
#pragma unroll
        for (int nf = 0; nf < 2; ++nf) {
            f32x4 z = {0.f, 0.f, 0.f, 0.f};
            acc[mf][nf] = z;
        }

    FragBuf B0, B1, B2;

    auto LOADF = [&](FragBuf& d, int Kc) {
#pragma unroll
        for (int mf = 0; mf < 4; ++mf)
            d.a[mf] = *(const bf16x8*)(aLane + (size_t)((R0 + mf) * 32 + Kc) * 512);
#pragma unroll
        for (int nf = 0; nf < 2; ++nf)
            d.b[nf] = *(const bf16x8*)(bLane + (size_t)((Nn0 + nf) * 32 + Kc) * 512);
    };
    auto MFMA = [&](const FragBuf& s) {
#pragma unroll
        for (int mf = 0; mf < 4; ++mf)
#pragma unroll
            for (int nf = 0; nf < 2; ++nf)
                acc[mf][nf] = __builtin_amdgcn_mfma_f32_16x16x32_bf16(
                    s.a[mf], s.b[nf], acc[mf][nf], 0, 0, 0);
    };

    // 32 K-steps (Kc = k/32), distance-2 prefetch, all indices static
    LOADF(B0, 0);
    LOADF(B1, 1);
#pragma unroll
    for (int s = 0; s < 30; s += 3) {
        LOADF(B2, s + 2); MFMA(B0);
        LOADF(B0, s + 3); MFMA(B1);
        LOADF(B1, s + 4); MFMA(B2);
    }
    MFMA(B0);   // step 30
    MFMA(B1);   // step 31

    // epilogue: C/D layout col = lane&15, row = (lane>>4)*4 + i
#pragma unroll
    for (int mf = 0; mf < 4; ++mf) {
        const int row0 = bm + wm * 64 + mf * 16 + (lq << 2);
#pragma unroll
        for (int nf = 0; nf < 2; ++nf) {
            const int col = bn + wn * 32 + nf * 16 + lrow;
#pragma unroll
            for (int i = 0; i < 4; ++i)
                C[(size_t)(row0 + i) * Ntot + col] = acc[mf][nf][i];
        }
    }
}

// ============================================================================
// Fallback (ws too small): round-2 fused kernel (proven correct, ~33 us)
// ============================================================================
static constexpr int FBM = 128, FBN = 128, FBK = 64, FBKP = 72;

__global__ __launch_bounds__(512, 2)
void vproj_fused_kernel(const float* __restrict__ A, const float* __restrict__ W,
                        float* __restrict__ C)
{
    __shared__ bf16_t As[2][FBM][FBKP];
    __shared__ bf16_t Bs[2][FBN][FBKP];

    const int t = threadIdx.x, lane = t & 63, wave = t >> 6;
    const int wm = wave >> 2, wn = wave & 3;
    const int tile = (blockIdx.x & 7) * 32 + (blockIdx.x >> 3);
    const int bm = (tile >> 3) * FBM, bn = (tile & 7) * FBN;

    const int bhead = t >> 8, brem = t & 255;
    const int bkq = brem >> 4, baq = brem & 15;
    const float* const wbase = W + ((size_t)((bn >> 6) + bhead)) * (Ktot * 64)
                                 + (size_t)(bkq * 4) * 64 + baq * 4;
    f32x4 avreg[4], bvreg[4];

    auto load_tile = [&](int k0) {
#pragma unroll
        for (int r = 0; r < 4; ++r) {
            const int idx = r * 512 + t;
            avreg[r] = *(const f32x4*)(A + (size_t)(bm + (idx >> 4)) * Ktot + k0 + (idx & 15) * 4);
        }
        const float* wp = wbase + (size_t)k0 * 64;
#pragma unroll
        for (int r = 0; r < 4; ++r) bvreg[r] = *(const f32x4*)(wp + r * 64);
    };
    auto store_tile = [&](int buf) {
#pragma unroll
        for (int r = 0; r < 4; ++r) {
            const int idx = r * 512 + t;
            bf16_t* dst = &As[buf][idx >> 4][(idx & 15) * 4];
            dst[0] = (bf16_t)avreg[r][0]; dst[1] = (bf16_t)avreg[r][1];
            dst[2] = (bf16_t)avreg[r][2]; dst[3] = (bf16_t)avreg[r][3];
        }
#pragma unroll
        for (int j = 0; j < 4; ++j) {
            bf16_t* dst = &Bs[buf][bhead * 64 + baq * 4 + j][bkq * 4];
            dst[0] = (bf16_t)bvreg[0][j]; dst[1] = (bf16_t)bvreg[1][j];
            dst[2] = (bf16_t)bvreg[2][j]; dst[3] = (bf16_t)bvreg[3][j];
        }
    };

    f32x4 acc[4][2];
#pragma unroll
    for (int mf = 0; mf < 4; ++mf)
#pragma unroll
        for (int nf = 0; nf < 2; ++nf) { f32x4 z = {0,0,0,0}; acc[mf][nf] = z; }

    const int lrow = lane & 15, lkb = (lane >> 4) << 3;
    load_tile(0); store_tile(0); __syncthreads();

    for (int tI = 0; tI < Ktot / FBK; ++tI) {
        const int cur = tI & 1;
        if (tI + 1 < Ktot / FBK) load_tile((tI + 1) * FBK);
#pragma unroll
        for (int kk = 0; kk < 2; ++kk) {
            bf16x8 af[4], bfr[2];
#pragma unroll
            for (int mf = 0; mf < 4; ++mf)
                af[mf] = *(const bf16x8*)&As[cur][wm * 64 + mf * 16 + lrow][kk * 32 + lkb];
#pragma unroll
            for (int nf = 0; nf < 2; ++nf)
                bfr[nf] = *(const bf16x8*)&Bs[cur][wn * 32 + nf * 16 + lrow][kk * 32 + lkb];
#pragma unroll
            for (int mf = 0; mf < 4; ++mf)
#pragma unroll
                for (int nf = 0; nf < 2; ++nf)
                    acc[mf][nf] = __builtin_amdgcn_mfma_f32_16x16x32_bf16(
                        af[mf], bfr[nf], acc[mf][nf], 0, 0, 0);
        }
        if (tI + 1 < Ktot / FBK) store_tile(cur ^ 1);
        __syncthreads();
    }
#pragma unroll
    for (int mf = 0; mf < 4; ++mf) {
        const int row0 = bm + wm * 64 + mf * 16 + ((lane >> 4) << 2);
#pragma unroll
        for (int nf = 0; nf < 2; ++nf) {
            const int col = bn + wn * 32 + nf * 16 + (lane & 15);
#pragma unroll
            for (int i = 0; i < 4; ++i)
                C[(size_t)(row0 + i) * Ntot + col] = acc[mf][nf][i];
        }
    }
}

extern "C" void kernel_launch(void* const* d_in, const int* in_sizes, int n_in,
                              void* d_out, int out_size, void* d_ws, size_t ws_size,
                              hipStream_t stream) {
    (void)in_sizes; (void)n_in; (void)out_size;
    const float* V  = (const float*)d_in[2];   // [B,S,F] = [M][K]
    const float* Vw = (const float*)d_in[5];   // [H,F,A]
    float* out      = (float*)d_out;           // [B,S,H,A] = [M][N]

    const size_t abBytes = (size_t)Mtot * Ktot * sizeof(bf16_t);   // 8 MiB
    const size_t wtBytes = (size_t)Ntot * Ktot * sizeof(bf16_t);   // 2 MiB

    if (ws_size >= abBytes + wtBytes) {
        bf16_t* Abf = (bf16_t*)d_ws;
        bf16_t* Wbf = (bf16_t*)((char*)d_ws + abBytes);
        hipLaunchKernelGGL(prepass_frag_kernel, dim3(2048 + 512), dim3(256), 0,
                           stream, V, Vw, Abf, Wbf);
        hipLaunchKernelGGL(gemm_frag_kernel, dim3(512), dim3(256), 0, stream,
                           Abf, Wbf, out);
    } else {
        hipLaunchKernelGGL(vproj_fused_kernel, dim3(256), dim3(512), 0, stream,
                           V, Vw, out);
    }
}

// Round 10
// 29.462 us; speedup vs baseline: 1.9945x; 1.2120x over previous
//
#include <hip/hip_runtime.h>
#include <hip/hip_bf16.h>

typedef __bf16 bf16_t;
typedef __bf16 bf16x4 __attribute__((ext_vector_type(4)));
typedef __bf16 bf16x8 __attribute__((ext_vector_type(8)));
typedef float  f32x4  __attribute__((ext_vector_type(4)));

typedef __attribute__((address_space(1))) const void  gvoid_t;
typedef __attribute__((address_space(3))) void        lvoid_t;

static constexpr int Mtot = 4096;   // B*S
static constexpr int Ntot = 1024;   // H*A
static constexpr int Ktot = 1024;   // F

// out[b,s,h,a] = sum_f value_input[b,s,f] * v_w[h,f,a]
// (reference softmax over q integrates to exactly 1 in the final q-contraction)

// ============================================================================
// Prepass: Ab = bf16(A) [4096][1024]; Wt = bf16 transpose of W: [n=h*64+a][k]
// (proven correct R3/R4)
// ============================================================================
__global__ __launch_bounds__(256)
void prepass_kernel(const float* __restrict__ A, const float* __restrict__ W,
                    bf16_t* __restrict__ Ab, bf16_t* __restrict__ Wt)
{
    __shared__ float wtile[64][65];
    const int bid = blockIdx.x, t = threadIdx.x;

    if (bid < 1024) {
        const size_t base = (size_t)bid * 4096 + t * 4;
#pragma unroll
        for (int r = 0; r < 4; ++r) {
            const size_t i = base + (size_t)r * 1024;
            const f32x4 v = *(const f32x4*)(A + i);
            bf16x4 p = {(bf16_t)v[0], (bf16_t)v[1], (bf16_t)v[2], (bf16_t)v[3]};
            *(bf16x4*)(Ab + i) = p;
        }
    } else {
        const int wb = bid - 1024;        // 0..255
        const int head = wb >> 4;
        const int k0 = (wb & 15) * 64;
        const float* wsrc = W + (size_t)head * (Ktot * 64) + (size_t)k0 * 64;
#pragma unroll
        for (int i = 0; i < 4; ++i) {
            const int idx = i * 256 + t;
            const int kr = idx >> 4, a4 = (idx & 15) * 4;
            const f32x4 v = *(const f32x4*)(wsrc + (size_t)kr * 64 + a4);
            wtile[kr][a4 + 0] = v[0]; wtile[kr][a4 + 1] = v[1];
            wtile[kr][a4 + 2] = v[2]; wtile[kr][a4 + 3] = v[3];
        }
        __syncthreads();
#pragma unroll
        for (int i = 0; i < 4; ++i) {
            const int idx = i * 256 + t;
            const int ar = idx >> 4, kc = (idx & 15) * 4;
            bf16x4 p = {(bf16_t)wtile[kc + 0][ar], (bf16_t)wtile[kc + 1][ar],
                        (bf16_t)wtile[kc + 2][ar], (bf16_t)wtile[kc + 3][ar]};
            *(bf16x4*)(Wt + (size_t)(head * 64 + ar) * Ktot + k0 + kc) = p;
        }
    }
}

// ============================================================================
// GEMM: R4's proven structure (global_load_lds staging, XOR swizzle, single
// __syncthreads per K-step) with BM=BN=64 -> grid 1024 = 4 blocks/CU
// (16 waves/CU) for latency hiding. LDS 32KB/block (4x32=128 <= 160KB).
// 4 waves in 2x2, wave-tile 32x32 (acc 2x2 frags).
// ============================================================================
__global__ __launch_bounds__(256, 4)
void gemm_bf16_kernel(const bf16_t* __restrict__ Ab, const bf16_t* __restrict__ Bt,
                      float* __restrict__ C)
{
    __shared__ bf16_t As[2][64 * 64];   // [row][64k], 128B rows, swizzled content
    __shared__ bf16_t Bs[2][64 * 64];   // [n][64k]

    const int t = threadIdx.x, lane = t & 63, wave = t >> 6;
    const int wm = wave & 1, wn = wave >> 1;

    // XCD swizzle: 1024 wgs; XCD x owns g in [128x,128x+128) = 8 M-panels
    // (A-slice 1MB) x all 16 N (Wt 2MB) -> 3MB < 4MB per-XCD L2
    const int g  = (blockIdx.x & 7) * 128 + (blockIdx.x >> 3);
    const int by = g >> 4, bx = g & 15;
    const int bm = by * 64, bn = bx * 64;

    const int lrow = lane & 15;
    const int lq   = lane >> 4;

    f32x4 acc[2][2];
#pragma unroll
    for (int mf = 0; mf < 2; ++mf)
#pragma unroll
        for (int nf = 0; nf < 2; ++nf) {
            f32x4 z = {0.f, 0.f, 0.f, 0.f};
            acc[mf][nf] = z;
        }

    // 4 global_load_lds per thread per STAGE (2 A + 2 B)
    auto STAGE = [&](int buf, int k0) {
#pragma unroll
        for (int j = 0; j < 2; ++j) {
            const int chunk = (wave * 2 + j) * 64 + lane;        // 0..511
            const int row = chunk >> 3;
            const int kb  = ((chunk & 7) ^ (row & 7)) * 8;        // swizzled src col
            const bf16_t* gp = Ab + (size_t)(bm + row) * Ktot + k0 + kb;
            __builtin_amdgcn_global_load_lds((gvoid_t*)gp,
                (lvoid_t*)&As[buf][(wave * 2 + j) * 512], 16, 0, 0);
        }
#pragma unroll
        for (int j = 0; j < 2; ++j) {
            const int chunk = (wave * 2 + j) * 64 + lane;
            const int row = chunk >> 3;
            const int kb  = ((chunk & 7) ^ (row & 7)) * 8;
            const bf16_t* gp = Bt + (size_t)(bn + row) * Ktot + k0 + kb;
            __builtin_amdgcn_global_load_lds((gvoid_t*)gp,
                (lvoid_t*)&Bs[buf][(wave * 2 + j) * 512], 16, 0, 0);
        }
    };

    STAGE(0, 0);
    __syncthreads();

    constexpr int NT = Ktot / 64;   // 16
    for (int tI = 0; tI < NT; ++tI) {
        const int cur = tI & 1;
        if (tI + 1 < NT) STAGE(cur ^ 1, (tI + 1) * 64);

#pragma unroll
        for (int kk = 0; kk < 2; ++kk) {
            const int c16 = kk * 4 + lq;          // 16B-column 0..7
            bf16x8 af[2], bfr[2];
#pragma unroll
            for (int mf = 0; mf < 2; ++mf) {
                const int R = wm * 32 + mf * 16 + lrow;
                af[mf] = *(const bf16x8*)&As[cur][R * 64 + ((c16 ^ (R & 7)) << 3)];
            }
#pragma unroll
            for (int nf = 0; nf < 2; ++nf) {
                const int R = wn * 32 + nf * 16 + lrow;
                bfr[nf] = *(const bf16x8*)&Bs[cur][R * 64 + ((c16 ^ (R & 7)) << 3)];
            }
            __builtin_amdgcn_s_setprio(1);
#pragma unroll
            for (int mf = 0; mf < 2; ++mf)
#pragma unroll
                for (int nf = 0; nf < 2; ++nf)
                    acc[mf][nf] = __builtin_amdgcn_mfma_f32_16x16x32_bf16(
                        af[mf], bfr[nf], acc[mf][nf], 0, 0, 0);
            __builtin_amdgcn_s_setprio(0);
        }
        __syncthreads();   // drains vmcnt (next tile staged) + lgkm
    }

    // epilogue: C/D layout col = lane&15, row = (lane>>4)*4 + i
#pragma unroll
    for (int mf = 0; mf < 2; ++mf) {
        const int row0 = bm + wm * 32 + mf * 16 + (lq << 2);
#pragma unroll
        for (int nf = 0; nf < 2; ++nf) {
            const int col = bn + wn * 32 + nf * 16 + lrow;
#pragma unroll
            for (int i = 0; i < 4; ++i)
                C[(size_t)(row0 + i) * Ntot + col] = acc[mf][nf][i];
        }
    }
}

// ============================================================================
// Fallback (ws too small): round-2 fused kernel (proven correct, ~33 us)
// ============================================================================
static constexpr int FBM = 128, FBN = 128, FBK = 64, FBKP = 72;

__global__ __launch_bounds__(512, 2)
void vproj_fused_kernel(const float* __restrict__ A, const float* __restrict__ W,
                        float* __restrict__ C)
{
    __shared__ bf16_t As[2][FBM][FBKP];
    __shared__ bf16_t Bs[2][FBN][FBKP];

    const int t = threadIdx.x, lane = t & 63, wave = t >> 6;
    const int wm = wave >> 2, wn = wave & 3;
    const int tile = (blockIdx.x & 7) * 32 + (blockIdx.x >> 3);
    const int bm = (tile >> 3) * FBM, bn = (tile & 7) * FBN;

    const int bhead = t >> 8, brem = t & 255;
    const int bkq = brem >> 4, baq = brem & 15;
    const float* const wbase = W + ((size_t)((bn >> 6) + bhead)) * (Ktot * 64)
                                 + (size_t)(bkq * 4) * 64 + baq * 4;
    f32x4 avreg[4], bvreg[4];

    auto load_tile = [&](int k0) {
#pragma unroll
        for (int r = 0; r < 4; ++r) {
            const int idx = r * 512 + t;
            avreg[r] = *(const f32x4*)(A + (size_t)(bm + (idx >> 4)) * Ktot + k0 + (idx & 15) * 4);
        }
        const float* wp = wbase + (size_t)k0 * 64;
#pragma unroll
        for (int r = 0; r < 4; ++r) bvreg[r] = *(const f32x4*)(wp + r * 64);
    };
    auto store_tile = [&](int buf) {
#pragma unroll
        for (int r = 0; r < 4; ++r) {
            const int idx = r * 512 + t;
            bf16_t* dst = &As[buf][idx >> 4][(idx & 15) * 4];
            dst[0] = (bf16_t)avreg[r][0]; dst[1] = (bf16_t)avreg[r][1];
            dst[2] = (bf16_t)avreg[r][2]; dst[3] = (bf16_t)avreg[r][3];
        }
#pragma unroll
        for (int j = 0; j < 4; ++j) {
            bf16_t* dst = &Bs[buf][bhead * 64 + baq * 4 + j][bkq * 4];
            dst[0] = (bf16_t)bvreg[0][j]; dst[1] = (bf16_t)bvreg[1][j];
            dst[2] = (bf16_t)bvreg[2][j]; dst[3] = (bf16_t)bvreg[3][j];
        }
    };

    f32x4 acc[4][2];
#pragma unroll
    for (int mf = 0; mf < 4; ++mf)
#pragma unroll
        for (int nf = 0; nf < 2; ++nf) { f32x4 z = {0,0,0,0}; acc[mf][nf] = z; }

    const int lrow = lane & 15, lkb = (lane >> 4) << 3;
    load_tile(0); store_tile(0); __syncthreads();

    for (int tI = 0; tI < Ktot / FBK; ++tI) {
        const int cur = tI & 1;
        if (tI + 1 < Ktot / FBK) load_tile((tI + 1) * FBK);
#pragma unroll
        for (int kk = 0; kk < 2; ++kk) {
            bf16x8 af[4], bfr[2];
#pragma unroll
            for (int mf = 0; mf < 4; ++mf)
                af[mf] = *(const bf16x8*)&As[cur][wm * 64 + mf * 16 + lrow][kk * 32 + lkb];
#pragma unroll
            for (int nf = 0; nf < 2; ++nf)
                bfr[nf] = *(const bf16x8*)&Bs[cur][wn * 32 + nf * 16 + lrow][kk * 32 + lkb];
#pragma unroll
            for (int mf = 0; mf < 4; ++mf)
#pragma unroll
                for (int nf = 0; nf < 2; ++nf)
                    acc[mf][nf] = __builtin_amdgcn_mfma_f32_16x16x32_bf16(
                        af[mf], bfr[nf], acc[mf][nf], 0, 0, 0);
        }
        if (tI + 1 < Ktot / FBK) store_tile(cur ^ 1);
        __syncthreads();
    }
#pragma unroll
    for (int mf = 0; mf < 4; ++mf) {
        const int row0 = bm + wm * 64 + mf * 16 + ((lane >> 4) << 2);
#pragma unroll
        for (int nf = 0; nf < 2; ++nf) {
            const int col = bn + wn * 32 + nf * 16 + (lane & 15);
#pragma unroll
            for (int i = 0; i < 4; ++i)
                C[(size_t)(row0 + i) * Ntot + col] = acc[mf][nf][i];
        }
    }
}

extern "C" void kernel_launch(void* const* d_in, const int* in_sizes, int n_in,
                              void* d_out, int out_size, void* d_ws, size_t ws_size,
                              hipStream_t stream) {
    (void)in_sizes; (void)n_in; (void)out_size;
    const float* V  = (const float*)d_in[2];   // [B,S,F] = [M][K]
    const float* Vw = (const float*)d_in[5];   // [H,F,A]
    float* out      = (float*)d_out;           // [B,S,H,A] = [M][N]

    const size_t abBytes = (size_t)Mtot * Ktot * sizeof(bf16_t);   // 8 MiB
    const size_t wtBytes = (size_t)Ntot * Ktot * sizeof(bf16_t);   // 2 MiB

    if (ws_size >= abBytes + wtBytes) {
        bf16_t* Ab = (bf16_t*)d_ws;
        bf16_t* Wt = (bf16_t*)((char*)d_ws + abBytes);
        hipLaunchKernelGGL(prepass_kernel, dim3(1024 + 256), dim3(256), 0, stream,
                           V, Vw, Ab, Wt);
        hipLaunchKernelGGL(gemm_bf16_kernel, dim3((Mtot / 64) * (Ntot / 64)),
                           dim3(256), 0, stream, Ab, Wt, out);
    } else {
        hipLaunchKernelGGL(vproj_fused_kernel, dim3(256), dim3(512), 0, stream,
                           V, Vw, out);
    }
}